// Round 1
// baseline (327.847 us; speedup 1.0000x reference)
//
#include <hip/hip_runtime.h>

#define NIB_SCALE 100.0f

__device__ __forceinline__ float bcast16(float v, int srcLane) {
    return __shfl(v, srcLane, 16);
}

__device__ __forceinline__ float rmax16(float v) {
    #pragma unroll
    for (int m = 1; m < 16; m <<= 1) v = fmaxf(v, __shfl_xor(v, m, 16));
    return v;
}

__device__ __forceinline__ float rsum16(float v) {
    #pragma unroll
    for (int m = 1; m < 16; m <<= 1) v += __shfl_xor(v, m, 16);
    return v;
}

// lane k of each 16-lane group holds x[e] = V[16*e + k] (e = high nibble, k = low).
// Returns, in lane k, the high-group sum: sum_j V[16*k + j].
// Butterfly transpose-reduce: 15 shuffles, 15 adds.
__device__ __forceinline__ float transposeReduce16(const float x[16], int k) {
    float w[16];
    #pragma unroll
    for (int e = 0; e < 16; ++e) w[e] = x[e];
    #pragma unroll
    for (int d = 0; d < 4; ++d) {
        const int m = 1 << d;
        const int bit = (k >> d) & 1;
        const int n = 16 >> (d + 1);
        #pragma unroll
        for (int j = 0; j < n; ++j) {
            // keep the half matching my lane's bit d; send the half the partner keeps
            float keep = bit ? w[2 * j + 1] : w[2 * j];
            float send = bit ? w[2 * j]     : w[2 * j + 1];
            float recv = __shfl_xor(send, m, 16);
            w[j] = keep + recv;
        }
    }
    return w[0];
}

// Sharp softmax over the 16 values distributed one-per-lane in a 16-lane group.
__device__ __forceinline__ float softmax16(float v) {
    float m = rmax16(v);
    float e = __expf(NIB_SCALE * (v - m));
    float s = rsum16(e);
    return e / s;
}

__global__ __launch_bounds__(256) void nalu_kernel(const float* __restrict__ A,
                                                   const float* __restrict__ B,
                                                   float* __restrict__ O,
                                                   int nrows) {
    const int tid = threadIdx.x;
    const int k = tid & 15;                       // lane within 16-lane row group
    const int row = blockIdx.x * 16 + (tid >> 4); // one row per 16-lane group
    if (row >= nrows) return;
    const long base = (long)row * 1024;

    // Incoming carry distribution, already softmax-sharpened:
    // carry vec = [1,0]  ->  pc1 = 1/(1+e^{100}) = 0 (ref value 3.7e-44, negligible)
    float pc0 = 1.0f, pc1 = 0.0f;

    #pragma unroll
    for (int byte = 0; byte < 4; ++byte) {
        const float* pa = A + base + byte * 256;
        const float* pb = B + base + byte * 256;

        float xa[16], xb[16];
        #pragma unroll
        for (int e = 0; e < 16; ++e) xa[e] = pa[16 * e + k];  // coalesced 64B/group
        #pragma unroll
        for (int e = 0; e < 16; ++e) xb[e] = pb[16 * e + k];

        // b2n: low-nibble sums are lane-local; high-nibble sums via transpose-reduce
        float al = 0.f, bl = 0.f;
        #pragma unroll
        for (int e = 0; e < 16; ++e) al += xa[e];
        #pragma unroll
        for (int e = 0; e < 16; ++e) bl += xb[e];
        float ah = transposeReduce16(xa, k);
        float bh = transposeReduce16(xb, k);

        // factorized sharp softmaxes (exactly equals the joint 512-softmax)
        float pal = softmax16(al);
        float pbl = softmax16(bl);
        float pah = softmax16(ah);
        float pbh = softmax16(bh);

        // circular convolution r[k] = sum_a p[a] * q[(k-a)&15]  (low and high)
        float rl = 0.f, rh = 0.f;
        #pragma unroll
        for (int a = 0; a < 16; ++a) {
            float pa_l = bcast16(pal, a);
            float pa_h = bcast16(pah, a);
            float pb_l = bcast16(pbl, (k - a) & 15);
            float pb_h = bcast16(pbh, (k - a) & 15);
            rl = fmaf(pa_l, pb_l, rl);
            rh = fmaf(pa_h, pb_h, rh);
        }

        // overflow masses: T[k] = sum_{b>=k} q[b] (suffix scan), then
        // OV15 = sum_{a+b>=15} p[a]q[b] = sum_a p[a]*T[15-a];  OV16 = OV15 - sum_{a+b=15}
        float Tl = pbl, Th = pbh;
        #pragma unroll
        for (int d = 1; d < 16; d <<= 1) {
            float tl = __shfl_down(Tl, d, 16);
            float th = __shfl_down(Th, d, 16);
            if (k + d < 16) { Tl += tl; Th += th; }
        }
        float T15l = bcast16(Tl, 15 - k);
        float T15h = bcast16(Th, 15 - k);
        float B15l = bcast16(pbl, 15 - k);
        float B15h = bcast16(pbh, 15 - k);
        float ov15l = rsum16(pal * T15l);
        float c15l  = rsum16(pal * B15l);
        float ov15h = rsum16(pah * T15h);
        float c15h  = rsum16(pah * B15h);
        float ov16l = ov15l - c15l;
        float ov16h = ov15h - c15h;

        // low nibble add with incoming carry (pc0,pc1)
        float rlm1  = bcast16(rl, (k - 1) & 15);
        float slow  = pc0 * rl + pc1 * rlm1;
        float coutl = pc0 * ov16l + pc1 * ov15l;

        // sharpen carry: pc' = softmax(100*[1-cout, cout]) -> sigmoid form
        float e1  = __expf(NIB_SCALE * (1.0f - 2.0f * coutl));
        float qc1 = 1.0f / (1.0f + e1);
        float qc0 = 1.0f - qc1;

        // high nibble add
        float rhm1  = bcast16(rh, (k - 1) & 15);
        float shigh = qc0 * rh + qc1 * rhm1;
        float couth = qc0 * ov16h + qc1 * ov15h;

        // carry for next byte
        float e2 = __expf(NIB_SCALE * (1.0f - 2.0f * couth));
        pc1 = 1.0f / (1.0f + e2);
        pc0 = 1.0f - pc1;

        // n2b: output[(h<<4)|l] = psh[h] * psl[l]
        float psl = softmax16(slow);
        float psh = softmax16(shigh);

        float* po = O + base + byte * 256;
        float l0 = bcast16(psl, 4 * (k & 3) + 0);
        float l1 = bcast16(psl, 4 * (k & 3) + 1);
        float l2 = bcast16(psl, 4 * (k & 3) + 2);
        float l3 = bcast16(psl, 4 * (k & 3) + 3);
        #pragma unroll
        for (int c = 0; c < 4; ++c) {
            float hs = bcast16(psh, 4 * c + (k >> 2));
            float4 o4 = make_float4(hs * l0, hs * l1, hs * l2, hs * l3);
            *(float4*)(po + 64 * c + 4 * k) = o4;  // 16 lanes x 16B = 256B contiguous
        }
    }
}

extern "C" void kernel_launch(void* const* d_in, const int* in_sizes, int n_in,
                              void* d_out, int out_size, void* d_ws, size_t ws_size,
                              hipStream_t stream) {
    const float* A = (const float*)d_in[0];
    const float* B = (const float*)d_in[1];
    float* O = (float*)d_out;
    int nrows = in_sizes[0] / 1024;          // [B,4,256] -> B
    int grid = (nrows + 15) / 16;            // 16 rows per 256-thread block
    nalu_kernel<<<grid, 256, 0, stream>>>(A, B, O, nrows);
}